// Round 4
// baseline (5732.526 us; speedup 1.0000x reference)
//
#include <hip/hip_runtime.h>
#include <hip/hip_bf16.h>
#include <math.h>

// Problem constants
#define BB 64
#define TT 256
#define EE 300
#define DD 600
#define KP 608        // K padded to 19*32 for MFMA
#define HH 512
#define G4 2048
#define LL 9
#define NT (BB*TT)

typedef __attribute__((ext_vector_type(8))) short short8;   // 8 bf16
typedef __attribute__((ext_vector_type(4))) float floatx4;  // MFMA acc
typedef __attribute__((ext_vector_type(4))) unsigned uintx4;

// ---------------- Workspace layout (bytes) ----------------
#define XZF_OFF  ((size_t)0)
#define XZ_BYTES ((size_t)NT * G4 * 2)                  // 67108864
#define XZB_OFF  (XZF_OFF + XZ_BYTES)
#define HSR_OFF  (XZB_OFF + XZ_BYTES)                   // hs region, 33554432
#define HS_BYTES ((size_t)NT * HH * 2)                  // 16777216
#define HSF_OFF  (HSR_OFF)
#define HSB_OFF  (HSR_OFF + HS_BYTES)
// aliases inside hs region (dead before lstm writes hs):
#define XG_OFF   (HSR_OFF)                              // 16384*608*2
#define WKT_OFF  (HSR_OFF + 19922944)                   // 2*2048*608*2
#define WRT_OFF  (HSR_OFF + (size_t)2 * HS_BYTES)       // 2*2048*512*2 = 4194304
#define BK_OFF   (WRT_OFF + 4194304)                    // backup tagged: 524288
#define FAST_OFF (BK_OFF + 524288)                      // fast clean bf16: 262144 (512K reserved)
#define EX_BYTES ((size_t)2 * 2 * BB * HH * 4)          // 524288 each
#define FLAGS_OFF (FAST_OFF + 524288)                   // 8 groups * 32 u32 = 1024
// WdT aliases xz_f (dead after lstm), written post-lstm:
#define WDT_OFF  XZF_OFF                                // 16*1024*2 = 32768

// Output layout (floats)
#define OUT_LOGITS 0
#define OUT_LENS   (BB*TT*LL)
#define OUT_LL     (OUT_LENS + BB)
#define OUT_TAGS   (OUT_LL + BB)

// ---------------------------------------------------------------------------
// Prep 1: gather embeddings -> xg[n][608] bf16 (zero-padded K)
// ---------------------------------------------------------------------------
__global__ __launch_bounds__(256) void prep_xg(
    const int* __restrict__ text, const int* __restrict__ sent,
    const float* __restrict__ wemb, const float* __restrict__ semb,
    __hip_bfloat16* __restrict__ xg)
{
    int n = blockIdx.x;
    int ti = text[n], si = sent[n];
    __hip_bfloat16* o = xg + (size_t)n * KP;
    for (int k = threadIdx.x; k < KP; k += 256) {
        float v = 0.f;
        if (k < EE)      v = wemb[(size_t)ti * EE + k];
        else if (k < DD) v = semb[(size_t)si * EE + (k - EE)];
        o[k] = __float2bfloat16(v);
    }
}

// ---------------------------------------------------------------------------
// Prep 2: LDS-tiled transpose + bf16 convert. W[dir]=[Din][2048] f32 ->
// out[dir]=[2048][Dpad] bf16
// ---------------------------------------------------------------------------
__global__ __launch_bounds__(256) void transpose_w(
    const float* __restrict__ Wf, const float* __restrict__ Wb,
    __hip_bfloat16* __restrict__ outT, int Din, int Dpad)
{
    int dir = blockIdx.z;
    const float* W = dir ? Wb : Wf;
    __hip_bfloat16* o = outT + (size_t)dir * G4 * Dpad;
    int n0 = blockIdx.x * 64, d0 = blockIdx.y * 64;
    __shared__ float tile[64][65];
    int c = threadIdx.x & 63, r4 = threadIdx.x >> 6;
    #pragma unroll
    for (int rr = 0; rr < 64; rr += 4) {
        int d = d0 + rr + r4;
        tile[rr + r4][c] = (d < Din) ? W[(size_t)d * G4 + n0 + c] : 0.f;
    }
    __syncthreads();
    #pragma unroll
    for (int rr = 0; rr < 64; rr += 4) {
        int n = n0 + rr + r4;
        int d = d0 + c;
        if (d < Dpad) o[(size_t)n * Dpad + d] = __float2bfloat16(tile[c][rr + r4]);
    }
}

// ---------------------------------------------------------------------------
// Prep 3 (post-lstm): WdT[16][1024] bf16, WdT[c][k] = Wd[k][c] (c<9 else 0)
// ---------------------------------------------------------------------------
__global__ __launch_bounds__(256) void prep_wdT(
    const float* __restrict__ Wd, __hip_bfloat16* __restrict__ WdT)
{
    for (int i = threadIdx.x + blockIdx.x * 256; i < 16 * 1024; i += gridDim.x * 256) {
        int nn = i >> 10, k = i & 1023;
        WdT[i] = __float2bfloat16(nn < LL ? Wd[(size_t)k * LL + nn] : 0.f);
    }
}

// ---------------------------------------------------------------------------
// Embed GEMM: 128x64 tile, 8 MFMA / 6 frag-loads per kc
// ---------------------------------------------------------------------------
__global__ __launch_bounds__(256) void embed_gemm(
    const __hip_bfloat16* __restrict__ xg,
    const __hip_bfloat16* __restrict__ WkT,
    const float* __restrict__ b_f, const float* __restrict__ b_b,
    __hip_bfloat16* __restrict__ xz_f, __hip_bfloat16* __restrict__ xz_b)
{
    int dir = blockIdx.z;
    const __hip_bfloat16* wt = WkT + (size_t)dir * G4 * KP;
    const float* bias = dir ? b_b : b_f;
    __hip_bfloat16* xz = dir ? xz_b : xz_f;

    int n0 = blockIdx.x * 128;
    int c0 = blockIdx.y * 64;
    int wave = threadIdx.x >> 6, lane = threadIdx.x & 63;
    int m0 = (wave & 1) * 64;
    int nn0 = (wave >> 1) * 32;
    int lm = lane & 15, lk8 = (lane >> 4) * 8;

    const short8 *ap[4], *bp2[2];
    #pragma unroll
    for (int i = 0; i < 4; ++i)
        ap[i] = (const short8*)(xg + (size_t)(n0 + m0 + i*16 + lm) * KP + lk8);
    #pragma unroll
    for (int i = 0; i < 2; ++i)
        bp2[i] = (const short8*)(wt + (size_t)(c0 + nn0 + i*16 + lm) * KP + lk8);

    floatx4 acc[4][2] = {};
    for (int kc = 0; kc < KP/32; ++kc) {
        short8 a0 = ap[0][kc*4], a1 = ap[1][kc*4], a2 = ap[2][kc*4], a3 = ap[3][kc*4];
        short8 b0 = bp2[0][kc*4], b1 = bp2[1][kc*4];
        acc[0][0] = __builtin_amdgcn_mfma_f32_16x16x32_bf16(a0, b0, acc[0][0], 0,0,0);
        acc[0][1] = __builtin_amdgcn_mfma_f32_16x16x32_bf16(a0, b1, acc[0][1], 0,0,0);
        acc[1][0] = __builtin_amdgcn_mfma_f32_16x16x32_bf16(a1, b0, acc[1][0], 0,0,0);
        acc[1][1] = __builtin_amdgcn_mfma_f32_16x16x32_bf16(a1, b1, acc[1][1], 0,0,0);
        acc[2][0] = __builtin_amdgcn_mfma_f32_16x16x32_bf16(a2, b0, acc[2][0], 0,0,0);
        acc[2][1] = __builtin_amdgcn_mfma_f32_16x16x32_bf16(a2, b1, acc[2][1], 0,0,0);
        acc[3][0] = __builtin_amdgcn_mfma_f32_16x16x32_bf16(a3, b0, acc[3][0], 0,0,0);
        acc[3][1] = __builtin_amdgcn_mfma_f32_16x16x32_bf16(a3, b1, acc[3][1], 0,0,0);
    }

    int lr = (lane >> 4) * 4;
    #pragma unroll
    for (int ni = 0; ni < 2; ++ni) {
        int col = c0 + nn0 + ni*16 + lm;
        float bs = bias[col];
        #pragma unroll
        for (int mi = 0; mi < 4; ++mi) {
            #pragma unroll
            for (int r = 0; r < 4; ++r) {
                int row = n0 + m0 + mi*16 + lr + r;
                xz[(size_t)row * G4 + col] = __float2bfloat16(acc[mi][ni][r] + bs);
            }
        }
    }
}

// ---------------------------------------------------------------------------
// sc0 (L1-bypass, L2-served) primitives
// ---------------------------------------------------------------------------
__device__ __forceinline__ void load4x16_sc0(const char* base, int tid, uintx4* v)
{
    #pragma unroll
    for (int q = 0; q < 4; ++q) {
        const char* ap = base + (size_t)(tid + 256 * q) * 16;
        asm volatile("global_load_dwordx4 %0, %1, off sc0"
                     : "=v"(v[q]) : "v"(ap));
    }
    asm volatile("s_waitcnt vmcnt(0)" ::: "memory");
}

__device__ __forceinline__ unsigned load_u32_sc0(const unsigned* p)
{
    unsigned r;
    asm volatile("global_load_dword %0, %1, off sc0\n\ts_waitcnt vmcnt(0)"
                 : "=v"(r) : "v"(p) : "memory");
    return r;
}

__device__ __forceinline__ void store_u32_sc0(unsigned* p, unsigned v)
{
    asm volatile("global_store_dword %0, %1, off sc0" :: "v"(p), "v"(v) : "memory");
}

// raw barrier (no vmcnt drain); empty memory-clobber asm + sched_barrier pin
// memory ops on both sides so nothing migrates across the s_barrier.
__device__ __forceinline__ void block_barrier_raw()
{
    asm volatile("" ::: "memory");
    __builtin_amdgcn_sched_barrier(0);
    __builtin_amdgcn_s_barrier();
    __builtin_amdgcn_sched_barrier(0);
    asm volatile("" ::: "memory");
}

// ---------------------------------------------------------------------------
// Persistent LSTM. 256 blocks x 256 threads, cooperative (R2 structure:
// 32 members x 16 cols, bfrag[16] = 64 VGPR, ~100 VGPR total, no spill).
// g = blk&7 (XCD residue class — all members share one L2), member = blk>>3.
// R4 protocol change (detection-round surgery; structure untouched):
//  - NO speculative data read. Consumer polls the 128B flag array first
//    (sleep(1) quantum), then does ONE clean 16KB bf16 read (4x dwordx4 per
//    thread) straight into the padded LDS tile. In lockstep the spec read
//    always failed — it was a pure 500cy L2-burst tax at 2x data volume.
//  - Fast payload is tag-FREE bf16 [2 slots][64][512]. Safety: flag=t is
//    stored only after the member's data stores were vmcnt-ack'd into the
//    shared L2 and a block barrier passed => flag implies data visible.
//    (Same-L2 ordering was already load-bearing for R2's post-poll read.)
//  - Tagged L3 backup path is byte-identical to R2 (layout, tags, polling);
//    flag-poll timeout falls back to it; fallcnt resets on success. Liveness
//    preserved, never deadlocks.
//  - Epilogue across all 256 threads (1 h/thread): halves the serial
//    transcendental chain; stores paired via __shfl_down so fast/bk/hs
//    writes remain dword/qword (no partial-line RMW).
//  - xz register pipeline + raw barriers B/C retained from R2.
// ---------------------------------------------------------------------------
__global__ __launch_bounds__(256, 1) void lstm_coop(
    const __hip_bfloat16* __restrict__ xz_f, const __hip_bfloat16* __restrict__ xz_b,
    const __hip_bfloat16* __restrict__ WrT,   // [2][2048][512]
    unsigned* __restrict__ bk,                // backup tagged [2][2][64][512] u32
    unsigned* __restrict__ fast,              // fast clean    [2][2][64][512] bf16
    unsigned* __restrict__ flags,             // [8 groups][32 members]
    __hip_bfloat16* __restrict__ hs_f, __hip_bfloat16* __restrict__ hs_b)
{
    int blk = blockIdx.x;
    int g = blk & 7;              // group = XCD residue class
    int member = blk >> 3;        // 0..31
    int dir = g >> 2;
    int r0 = (g & 3) * 16;
    int h0 = member * 16;
    int tid = threadIdx.x;
    int gate = tid >> 6, lane = tid & 63;
    int lm = lane & 15, lk8 = (lane >> 4) * 8;

    const __hip_bfloat16* xz = dir ? xz_b : xz_f;
    __hip_bfloat16* hs = dir ? hs_b : hs_f;
    const __hip_bfloat16* wrt = WrT + (size_t)dir * G4 * HH;
    unsigned* bkd = bk + (size_t)dir * 2 * BB * HH;
    char* fsd = (char*)fast + (size_t)dir * 2 * BB * HH * 2;   // bf16 bytes
    const unsigned* gfl = flags + (g << 5);
    unsigned* myflag = flags + (g << 5) + member;

    // persistent weight fragments (gate's 16 cols x full K=512): 64 VGPR
    short8 bfrag[16];
    {
        const short8* wp = (const short8*)(wrt + (size_t)(gate*HH + h0 + lm) * HH + lk8);
        #pragma unroll
        for (int kc = 0; kc < 16; ++kc) bfrag[kc] = wp[kc*4];
    }

    __shared__ unsigned short htile[16][520];
    __shared__ float zbuf[4][16][17];

    // epilogue ownership: thread -> (row, 1 col); c-state lives here
    int er = tid >> 4;            // 0..15
    int ecol = tid & 15;          // 0..15 (within member's 16 cols)
    float cst = 0.f;
    int zr = (lane >> 4) * 4;

    // xz pipeline: cur consumed this step, nxt prefetched for next step
    unsigned short xz_cur[4], xz_nxt[4];
    {
        int tok0 = dir ? (TT - 1) : 0;
        #pragma unroll
        for (int r = 0; r < 4; ++r) {
            int n = (r0 + zr + r) * TT + tok0;
            xz_cur[r] = *(const unsigned short*)(xz + (size_t)n * G4 + gate*HH + h0 + lm);
        }
    }

    bool fastok = true;
    int fallcnt = 0;

    // fast-read staging map: 16B chunk i = tid + 256*q over [16 rows][1024B]
    int frow = tid >> 6;              // + 4q -> row
    int fcol = (tid & 63) * 8;        // bf16 col of the 8-elem chunk

    for (int t = 0; t < TT; ++t) {
        int tok = dir ? (TT - 1 - t) : t;
        const unsigned long long pat =
            ((unsigned long long)(unsigned)t << 48) |
            ((unsigned long long)(unsigned)t << 16);

        bool ok = false;
        if (fastok) {
            // (1) poll 32 flags: 1 dword/lane/round, sleep(1) quantum
            unsigned need = (unsigned)t;
            bool flagok = false;
            for (int spin = 0; spin < 256; ++spin) {
                unsigned f = load_u32_sc0(gfl + (lane & 31));
                if (__all(f >= need)) { flagok = true; break; }
                __builtin_amdgcn_s_sleep(1);
            }
            if (flagok) {
                // (2) ONE clean 16KB read -> LDS (flag implies visible in L2)
                const char* fsrc = fsd + (size_t)(t & 1) * 65536 + (size_t)r0 * 1024;
                uintx4 v4[4];
                load4x16_sc0(fsrc, tid, v4);
                #pragma unroll
                for (int q = 0; q < 4; ++q)
                    *(uintx4*)&htile[frow + 4*q][fcol] = v4[q];
                ok = true;
                fallcnt = 0;
            } else if (++fallcnt >= 3) {
                fastok = false;
            }
        }
        if (!ok) {
            // proven backup: agent-scope tag-in-data poll at L3 (unchanged)
            size_t soff = (size_t)(t & 1) * BB * HH + (size_t)r0 * HH;
            const unsigned long long* bsrc = (const unsigned long long*)(bkd + soff);
            unsigned long long v[16];
            for (;;) {
                #pragma unroll
                for (int q = 0; q < 16; ++q)
                    v[q] = __hip_atomic_load(bsrc + tid + 256*q,
                            __ATOMIC_RELAXED, __HIP_MEMORY_SCOPE_AGENT);
                unsigned long long bad = 0;
                #pragma unroll
                for (int q = 0; q < 16; ++q)
                    bad |= (v[q] ^ pat) & 0xFFFF0000FFFF0000ULL;
                if (bad == 0) break;
                __builtin_amdgcn_s_sleep(2);
            }
            #pragma unroll
            for (int q = 0; q < 16; ++q) {
                unsigned lo = (unsigned)(v[q] & 0xffffu);
                unsigned hi = (unsigned)((v[q] >> 32) & 0xffffu);
                *(unsigned*)&htile[q][tid * 2] = lo | (hi << 16);
            }
        }
        __syncthreads();   // barrier A (vmcnt drain only hits old bk/hs stores)

        // prefetch xz(t+1): retires under MFMA+epilogue; off every drain point
        if (t + 1 < TT) {
            int tokn = dir ? (TT - 2 - t) : (t + 1);
            #pragma unroll
            for (int r = 0; r < 4; ++r) {
                int n = (r0 + zr + r) * TT + tokn;
                xz_nxt[r] = *(const unsigned short*)(xz + (size_t)n * G4 + gate*HH + h0 + lm);
            }
        }

        floatx4 acc = {};
        #pragma unroll
        for (int kc = 0; kc < 16; ++kc) {
            short8 a = *(const short8*)&htile[lm][kc * 32 + lk8];
            acc = __builtin_amdgcn_mfma_f32_16x16x32_bf16(a, bfrag[kc], acc, 0,0,0);
        }

        #pragma unroll
        for (int r = 0; r < 4; ++r) {
            float xv = __bfloat162float(__builtin_bit_cast(__hip_bfloat16, xz_cur[r]));
            zbuf[gate][zr + r][lm] = acc[r] + xv;
        }

        // barrier B: LDS-only handoff; must NOT drain the xz prefetch
        asm volatile("s_waitcnt lgkmcnt(0)" ::: "memory");
        block_barrier_raw();

        // epilogue: all 256 threads, 1 h-value each
        {
            float zi = zbuf[0][er][ecol];
            float zf = zbuf[1][er][ecol];
            float zg = zbuf[2][er][ecol];
            float zo = zbuf[3][er][ecol];
            float si = 1.f/(1.f+__expf(-zi));
            float sf = 1.f/(1.f+__expf(-zf));
            float so = 1.f/(1.f+__expf(-zo));
            cst = sf * cst + si * tanhf(zg);
            float hv = so * tanhf(cst);
            unsigned u = (unsigned)__builtin_bit_cast(unsigned short, __float2bfloat16(hv));
            unsigned un = __shfl_down(u, 1);     // neighbor col's value
            if ((tid & 1) == 0) {
                unsigned dpay = u | (un << 16);
                unsigned tg = (unsigned)(t + 1) << 16;
                unsigned long long bpay =
                    ((unsigned long long)(tg | un) << 32) | (unsigned long long)(tg | u);
                int slot = (t + 1) & 1;
                int col = h0 + ecol;             // even
                // fast (clean bf16, L2): store -> vmcnt ack
                store_u32_sc0((unsigned*)(fsd + (size_t)slot * 65536
                                          + (size_t)(r0 + er) * 1024 + col * 2), dpay);
                asm volatile("s_waitcnt vmcnt(0)" ::: "memory");
                // backup (L3, tagged) + hs off the critical path
                size_t eoff = (size_t)slot * BB * HH + (size_t)(r0 + er) * HH + col;
                __hip_atomic_store((unsigned long long*)(bkd + eoff), bpay,
                                   __ATOMIC_RELAXED, __HIP_MEMORY_SCOPE_AGENT);
                *(unsigned*)(hs + ((size_t)(r0 + er) * TT + tok) * HH + col) = dpay;
            } else {
                asm volatile("s_waitcnt vmcnt(0)" ::: "memory");  // xz prefetch only
            }
        }
        // barrier C (raw, no vmcnt): all fast stores ack'd -> flag
        block_barrier_raw();
        if (tid == 0)
            store_u32_sc0(myflag, (unsigned)(t + 1));

        #pragma unroll
        for (int r = 0; r < 4; ++r) xz_cur[r] = xz_nxt[r];
    }
}

// ---------------------------------------------------------------------------
// logits via MFMA: 64 tokens/block (4 waves x 16), K=1024, N=16 (9 used)
// ---------------------------------------------------------------------------
__global__ __launch_bounds__(256) void logits_kernel(
    const __hip_bfloat16* __restrict__ hs_f, const __hip_bfloat16* __restrict__ hs_b,
    const __hip_bfloat16* __restrict__ WdT, const float* __restrict__ bd,
    float* __restrict__ out)
{
    int n0 = blockIdx.x * 64;
    int wave = threadIdx.x >> 6, lane = threadIdx.x & 63;
    int lm = lane & 15, lk8 = (lane >> 4) * 8;
    int nw = n0 + wave * 16;
    const short8* af = (const short8*)(hs_f + (size_t)(nw + lm) * HH + lk8);
    const short8* ab = (const short8*)(hs_b + (size_t)(nw + lm) * HH + lk8);
    const short8* bw = (const short8*)(WdT + (size_t)lm * 1024 + lk8);
    floatx4 acc = {};
    #pragma unroll
    for (int kc = 0; kc < 16; ++kc) {
        acc = __builtin_amdgcn_mfma_f32_16x16x32_bf16(af[kc*4], bw[kc*4], acc, 0,0,0);
        acc = __builtin_amdgcn_mfma_f32_16x16x32_bf16(ab[kc*4], bw[(kc+16)*4], acc, 0,0,0);
    }
    if (lm < LL) {
        float bv = bd[lm];
        #pragma unroll
        for (int r = 0; r < 4; ++r) {
            int n = nw + (lane >> 4) * 4 + r;
            out[(size_t)n * LL + lm] = acc[r] + bv;
        }
    }
}

// ---------------------------------------------------------------------------
// CRF: fused lens + log-likelihood + Viterbi. One block/batch, 256 threads.
// ---------------------------------------------------------------------------
__global__ __launch_bounds__(256) void crf_kernel(
    const float* __restrict__ logits, const int* __restrict__ text,
    const int* __restrict__ labels, const float* __restrict__ trans,
    float* __restrict__ out_lens, float* __restrict__ out_ll,
    float* __restrict__ out_tags)
{
    int b = blockIdx.x, tid = threadIdx.x;
    const float* lg = logits + (size_t)b * TT * LL;
    const int* lab = labels + b * TT;

    __shared__ float lgs[TT * LL];
    __shared__ float trs[81];
    __shared__ unsigned char bps[255 * LL + 1];
    __shared__ float partial[256];
    __shared__ int ired[256];
    __shared__ float tagf[TT];

    for (int i = tid; i < TT * LL; i += 256) lgs[i] = lg[i];
    if (tid < 81) trs[tid] = trans[tid];
    ired[tid] = (text[b * TT + tid] != 0) ? 1 : 0;
    __syncthreads();
    for (int s = 128; s > 0; s >>= 1) {
        if (tid < s) ired[tid] += ired[tid + s];
        __syncthreads();
    }
    int len = ired[0];
    if (tid == 0) out_lens[b] = (float)len;

    float up = 0.f;
    for (int t = tid; t < TT; t += 256) {
        float m = (t < len) ? 1.f : 0.f;
        up += m * lgs[t * LL + lab[t]];
        if (t >= 1) up += m * trs[lab[t - 1] * LL + lab[t]];
    }
    partial[tid] = up;
    __syncthreads();
    for (int s = 128; s > 0; s >>= 1) {
        if (tid < s) partial[tid] += partial[tid + s];
        __syncthreads();
    }

    if (tid < 64) {
        int lane = tid;
        int j = (lane < LL) ? lane : 0;
        float trj[LL];
        #pragma unroll
        for (int i = 0; i < LL; ++i) trj[i] = trs[i * LL + j];
        float alpha = lgs[j];
        float vit = alpha;
        for (int t = 1; t < TT; ++t) {
            bool m = t < len;
            float lgv = lgs[t * LL + j];
            float ta[LL];
            float mx = -1e30f, bv = -1e30f; int bi = 0;
            #pragma unroll
            for (int i = 0; i < LL; ++i) {
                float av = __shfl(alpha, i);
                float vv = __shfl(vit, i);
                ta[i] = av + trj[i];
                mx = fmaxf(mx, ta[i]);
                float sv = vv + trj[i];
                if (sv > bv) { bv = sv; bi = i; }
            }
            float s = 0.f;
            #pragma unroll
            for (int i = 0; i < LL; ++i) s += __expf(ta[i] - mx);
            float newa = mx + __logf(s) + lgv;
            float newv = bv + lgv;
            if (m) { alpha = newa; vit = newv; }
            if (lane < LL) bps[(t - 1) * LL + lane] = (unsigned char)(m ? bi : lane);
        }
        float aX[LL], vX[LL];
        #pragma unroll
        for (int i = 0; i < LL; ++i) { aX[i] = __shfl(alpha, i); vX[i] = __shfl(vit, i); }
        if (lane == 0) {
            float mx = -1e30f;
            #pragma unroll
            for (int i = 0; i < LL; ++i) mx = fmaxf(mx, aX[i]);
            float s = 0.f;
            #pragma unroll
            for (int i = 0; i < LL; ++i) s += __expf(aX[i] - mx);
            out_ll[b] = partial[0] - (mx + __logf(s));

            float bvv = vX[0]; int last = 0;
            #pragma unroll
            for (int i = 1; i < LL; ++i) if (vX[i] > bvv) { bvv = vX[i]; last = i; }
            tagf[TT - 1] = (float)last;
            int tg = last;
            for (int s2 = TT - 2; s2 >= 0; --s2) {
                tg = bps[s2 * LL + tg];
                tagf[s2] = (float)tg;
            }
        }
    }
    __syncthreads();
    out_tags[b * TT + tid] = tagf[tid];
}

// ---------------------------------------------------------------------------
extern "C" void kernel_launch(void* const* d_in, const int* in_sizes, int n_in,
                              void* d_out, int out_size, void* d_ws, size_t ws_size,
                              hipStream_t stream)
{
    const int*   text  = (const int*)d_in[0];
    const int*   sent  = (const int*)d_in[1];
    const int*   labels= (const int*)d_in[2];
    const float* wemb  = (const float*)d_in[3];
    const float* semb  = (const float*)d_in[4];
    const float* Wk_f  = (const float*)d_in[5];
    const float* Wr_f  = (const float*)d_in[6];
    const float* b_f   = (const float*)d_in[7];
    const float* Wk_b  = (const float*)d_in[8];
    const float* Wr_b  = (const float*)d_in[9];
    const float* b_b   = (const float*)d_in[10];
    const float* Wd    = (const float*)d_in[11];
    const float* bd    = (const float*)d_in[12];
    const float* trans = (const float*)d_in[13];
    float* out = (float*)d_out;

    char* ws = (char*)d_ws;
    __hip_bfloat16* xz_f = (__hip_bfloat16*)(ws + XZF_OFF);
    __hip_bfloat16* xz_b = (__hip_bfloat16*)(ws + XZB_OFF);
    __hip_bfloat16* hs_f = (__hip_bfloat16*)(ws + HSF_OFF);
    __hip_bfloat16* hs_b = (__hip_bfloat16*)(ws + HSB_OFF);
    __hip_bfloat16* xg   = (__hip_bfloat16*)(ws + XG_OFF);
    __hip_bfloat16* WkT  = (__hip_bfloat16*)(ws + WKT_OFF);
    __hip_bfloat16* WrT  = (__hip_bfloat16*)(ws + WRT_OFF);
    unsigned*       bk   = (unsigned*)(ws + BK_OFF);
    unsigned*       fast = (unsigned*)(ws + FAST_OFF);
    unsigned*       flg  = (unsigned*)(ws + FLAGS_OFF);
    __hip_bfloat16* WdT  = (__hip_bfloat16*)(ws + WDT_OFF);

    prep_xg <<<NT,  256, 0, stream>>>(text, sent, wemb, semb, xg);
    transpose_w<<<dim3(G4/64, (KP+63)/64, 2), 256, 0, stream>>>(Wk_f, Wk_b, WkT, DD, KP);
    transpose_w<<<dim3(G4/64, HH/64, 2),      256, 0, stream>>>(Wr_f, Wr_b, WrT, HH, HH);
    // zero backup + fast + flags (tag/flag 0 == h(0) = 0)
    hipMemsetAsync(ws + BK_OFF, 0, 2 * EX_BYTES + 1024, stream);

    embed_gemm<<<dim3(NT/128, G4/64, 2), 256, 0, stream>>>(
        xg, WkT, b_f, b_b, xz_f, xz_b);

    {
        void* args[] = { (void*)&xz_f, (void*)&xz_b, (void*)&WrT,
                         (void*)&bk, (void*)&fast, (void*)&flg,
                         (void*)&hs_f, (void*)&hs_b };
        hipLaunchCooperativeKernel((const void*)lstm_coop, dim3(256), dim3(256),
                                   args, 0, stream);
    }

    prep_wdT<<<16, 256, 0, stream>>>(Wd, WdT);   // aliases dead xz_f
    logits_kernel<<<NT/64, 256, 0, stream>>>(hs_f, hs_b, WdT, bd, out + OUT_LOGITS);
    crf_kernel<<<BB, 256, 0, stream>>>(out + OUT_LOGITS, text, labels, trans,
                                       out + OUT_LENS, out + OUT_LL, out + OUT_TAGS);
}

// Round 6
// 1441.220 us; speedup vs baseline: 3.9775x; 3.9775x over previous
//
#include <hip/hip_runtime.h>
#include <hip/hip_bf16.h>
#include <math.h>

// Problem constants
#define BB 64
#define TT 256
#define EE 300
#define DD 600
#define KP 608        // K padded to 19*32 for MFMA
#define HH 512
#define G4 2048
#define LL 9
#define NT (BB*TT)

typedef __attribute__((ext_vector_type(8))) short short8;   // 8 bf16
typedef __attribute__((ext_vector_type(4))) float floatx4;  // MFMA acc

// ---------------- Workspace layout (bytes) ----------------
#define XZF_OFF  ((size_t)0)
#define XZ_BYTES ((size_t)NT * G4 * 2)                  // 67108864
#define XZB_OFF  (XZF_OFF + XZ_BYTES)
#define HSR_OFF  (XZB_OFF + XZ_BYTES)                   // hs region, 33554432
#define HS_BYTES ((size_t)NT * HH * 2)                  // 16777216
#define HSF_OFF  (HSR_OFF)
#define HSB_OFF  (HSR_OFF + HS_BYTES)
// aliases inside hs region (dead before lstm writes hs):
#define XG_OFF   (HSR_OFF)                              // 16384*608*2
#define WKT_OFF  (HSR_OFF + 19922944)                   // 2*2048*608*2
#define WRT_OFF  (HSR_OFF + (size_t)2 * HS_BYTES)       // 2*2048*512*2 = 4194304
#define BK_OFF   (WRT_OFF + 4194304)                    // backup tagged: 524288
#define FAST_OFF (BK_OFF + 524288)                      // fast tagged:   524288
#define EX_BYTES ((size_t)2 * 2 * BB * HH * 4)          // 524288 each
#define FLAGS_OFF (FAST_OFF + 524288)                   // 8 groups * 32 u32 = 1024
// WdT aliases xz_f (dead after lstm), written post-lstm:
#define WDT_OFF  XZF_OFF                                // 16*1024*2 = 32768

// Output layout (floats)
#define OUT_LOGITS 0
#define OUT_LENS   (BB*TT*LL)
#define OUT_LL     (OUT_LENS + BB)
#define OUT_TAGS   (OUT_LL + BB)

// ---------------------------------------------------------------------------
// Prep 1: gather embeddings -> xg[n][608] bf16 (zero-padded K)
// ---------------------------------------------------------------------------
__global__ __launch_bounds__(256) void prep_xg(
    const int* __restrict__ text, const int* __restrict__ sent,
    const float* __restrict__ wemb, const float* __restrict__ semb,
    __hip_bfloat16* __restrict__ xg)
{
    int n = blockIdx.x;
    int ti = text[n], si = sent[n];
    __hip_bfloat16* o = xg + (size_t)n * KP;
    for (int k = threadIdx.x; k < KP; k += 256) {
        float v = 0.f;
        if (k < EE)      v = wemb[(size_t)ti * EE + k];
        else if (k < DD) v = semb[(size_t)si * EE + (k - EE)];
        o[k] = __float2bfloat16(v);
    }
}

// ---------------------------------------------------------------------------
// Prep 2: LDS-tiled transpose + bf16 convert. W[dir]=[Din][2048] f32 ->
// out[dir]=[2048][Dpad] bf16
// ---------------------------------------------------------------------------
__global__ __launch_bounds__(256) void transpose_w(
    const float* __restrict__ Wf, const float* __restrict__ Wb,
    __hip_bfloat16* __restrict__ outT, int Din, int Dpad)
{
    int dir = blockIdx.z;
    const float* W = dir ? Wb : Wf;
    __hip_bfloat16* o = outT + (size_t)dir * G4 * Dpad;
    int n0 = blockIdx.x * 64, d0 = blockIdx.y * 64;
    __shared__ float tile[64][65];
    int c = threadIdx.x & 63, r4 = threadIdx.x >> 6;
    #pragma unroll
    for (int rr = 0; rr < 64; rr += 4) {
        int d = d0 + rr + r4;
        tile[rr + r4][c] = (d < Din) ? W[(size_t)d * G4 + n0 + c] : 0.f;
    }
    __syncthreads();
    #pragma unroll
    for (int rr = 0; rr < 64; rr += 4) {
        int n = n0 + rr + r4;
        int d = d0 + c;
        if (d < Dpad) o[(size_t)n * Dpad + d] = __float2bfloat16(tile[c][rr + r4]);
    }
}

// ---------------------------------------------------------------------------
// Prep 3 (post-lstm): WdT[16][1024] bf16, WdT[c][k] = Wd[k][c] (c<9 else 0)
// ---------------------------------------------------------------------------
__global__ __launch_bounds__(256) void prep_wdT(
    const float* __restrict__ Wd, __hip_bfloat16* __restrict__ WdT)
{
    for (int i = threadIdx.x + blockIdx.x * 256; i < 16 * 1024; i += gridDim.x * 256) {
        int nn = i >> 10, k = i & 1023;
        WdT[i] = __float2bfloat16(nn < LL ? Wd[(size_t)k * LL + nn] : 0.f);
    }
}

// ---------------------------------------------------------------------------
// Embed GEMM: 128x64 tile, 8 MFMA / 6 frag-loads per kc.
// R5: both directions computed in ONE block (inner dir loop) so the second
// pass's A-tile (155 KB) is an L2 hit — halves A-side L3/HBM traffic.
// Register pressure unchanged (acc reused per pass; A frags transient).
// ---------------------------------------------------------------------------
__global__ __launch_bounds__(256) void embed_gemm(
    const __hip_bfloat16* __restrict__ xg,
    const __hip_bfloat16* __restrict__ WkT,
    const float* __restrict__ b_f, const float* __restrict__ b_b,
    __hip_bfloat16* __restrict__ xz_f, __hip_bfloat16* __restrict__ xz_b)
{
    int n0 = blockIdx.x * 128;
    int c0 = blockIdx.y * 64;
    int wave = threadIdx.x >> 6, lane = threadIdx.x & 63;
    int m0 = (wave & 1) * 64;
    int nn0 = (wave >> 1) * 32;
    int lm = lane & 15, lk8 = (lane >> 4) * 8;

    const short8 *ap[4];
    #pragma unroll
    for (int i = 0; i < 4; ++i)
        ap[i] = (const short8*)(xg + (size_t)(n0 + m0 + i*16 + lm) * KP + lk8);

    for (int dir = 0; dir < 2; ++dir) {
        const __hip_bfloat16* wt = WkT + (size_t)dir * G4 * KP;
        const float* bias = dir ? b_b : b_f;
        __hip_bfloat16* xz = dir ? xz_b : xz_f;

        const short8 *bp2[2];
        #pragma unroll
        for (int i = 0; i < 2; ++i)
            bp2[i] = (const short8*)(wt + (size_t)(c0 + nn0 + i*16 + lm) * KP + lk8);

        floatx4 acc[4][2] = {};
        for (int kc = 0; kc < KP/32; ++kc) {
            short8 a0 = ap[0][kc*4], a1 = ap[1][kc*4], a2 = ap[2][kc*4], a3 = ap[3][kc*4];
            short8 b0 = bp2[0][kc*4], b1 = bp2[1][kc*4];
            acc[0][0] = __builtin_amdgcn_mfma_f32_16x16x32_bf16(a0, b0, acc[0][0], 0,0,0);
            acc[0][1] = __builtin_amdgcn_mfma_f32_16x16x32_bf16(a0, b1, acc[0][1], 0,0,0);
            acc[1][0] = __builtin_amdgcn_mfma_f32_16x16x32_bf16(a1, b0, acc[1][0], 0,0,0);
            acc[1][1] = __builtin_amdgcn_mfma_f32_16x16x32_bf16(a1, b1, acc[1][1], 0,0,0);
            acc[2][0] = __builtin_amdgcn_mfma_f32_16x16x32_bf16(a2, b0, acc[2][0], 0,0,0);
            acc[2][1] = __builtin_amdgcn_mfma_f32_16x16x32_bf16(a2, b1, acc[2][1], 0,0,0);
            acc[3][0] = __builtin_amdgcn_mfma_f32_16x16x32_bf16(a3, b0, acc[3][0], 0,0,0);
            acc[3][1] = __builtin_amdgcn_mfma_f32_16x16x32_bf16(a3, b1, acc[3][1], 0,0,0);
        }

        int lr = (lane >> 4) * 4;
        #pragma unroll
        for (int ni = 0; ni < 2; ++ni) {
            int col = c0 + nn0 + ni*16 + lm;
            float bs = bias[col];
            #pragma unroll
            for (int mi = 0; mi < 4; ++mi) {
                #pragma unroll
                for (int r = 0; r < 4; ++r) {
                    int row = n0 + m0 + mi*16 + lr + r;
                    xz[(size_t)row * G4 + col] = __float2bfloat16(acc[mi][ni][r] + bs);
                }
            }
        }
    }
}

// ---------------------------------------------------------------------------
// sc0 (L1-bypass, L2-served) pipelined primitives
// ---------------------------------------------------------------------------
__device__ __forceinline__ void load16_sc0(const unsigned long long* base,
                                           int tid, unsigned long long* v)
{
    #pragma unroll
    for (int q = 0; q < 16; ++q) {
        const unsigned long long* ap = base + tid + 256 * q;
        asm volatile("global_load_dwordx2 %0, %1, off sc0"
                     : "=v"(v[q]) : "v"(ap));
    }
    asm volatile("s_waitcnt vmcnt(0)" ::: "memory");
}

__device__ __forceinline__ void store_sc0(unsigned long long* p,
                                          unsigned long long val)
{
    asm volatile("global_store_dwordx2 %0, %1, off sc0"
                 :: "v"(p), "v"(val) : "memory");
}

__device__ __forceinline__ unsigned load_u32_sc0(const unsigned* p)
{
    unsigned r;
    asm volatile("global_load_dword %0, %1, off sc0\n\ts_waitcnt vmcnt(0)"
                 : "=v"(r) : "v"(p) : "memory");
    return r;
}

__device__ __forceinline__ void store_u32_sc0(unsigned* p, unsigned v)
{
    asm volatile("global_store_dword %0, %1, off sc0" :: "v"(p), "v"(v) : "memory");
}

// ---------------------------------------------------------------------------
// Persistent LSTM. 256 blocks x 256 threads, cooperative. (R0-verbatim:
// the verified 937 µs local optimum. Spec-read-first tagged protocol.)
// g = blk&7 (XCD residue class — confirmed L2-local by prior FETCH collapse),
// member = blk>>3. Fast path: (1) SPECULATIVE tagged-data read (1 RT when
// producers ahead); (2) on miss, poll 128B FLAG array (not the 32KB tile);
// (3) one final data read. Producer: fast+backup+hs stores -> drain barrier
// -> flag=t+1 (flag implies data visible in same L2). Backup (L3,
// tag-in-data): bounded flag spins fall back to it; sticky-disable after 3
// failed steps. Never deadlocks.
// ---------------------------------------------------------------------------
__global__ __launch_bounds__(256, 1) void lstm_coop(
    const __hip_bfloat16* __restrict__ xz_f, const __hip_bfloat16* __restrict__ xz_b,
    const __hip_bfloat16* __restrict__ WrT,   // [2][2048][512]
    unsigned* __restrict__ bk,                // backup tagged [2][2][64][512]
    unsigned* __restrict__ fast,              // fast   tagged [2][2][64][512]
    unsigned* __restrict__ flags,             // [8 groups][32 members]
    __hip_bfloat16* __restrict__ hs_f, __hip_bfloat16* __restrict__ hs_b)
{
    int blk = blockIdx.x;
    int g = blk & 7;              // group = XCD residue class
    int member = blk >> 3;        // 0..31
    int dir = g >> 2;
    int r0 = (g & 3) * 16;
    int h0 = member * 16;
    int tid = threadIdx.x;
    int gate = tid >> 6, lane = tid & 63;
    int lm = lane & 15, lk8 = (lane >> 4) * 8;

    const __hip_bfloat16* xz = dir ? xz_b : xz_f;
    __hip_bfloat16* hs = dir ? hs_b : hs_f;
    const __hip_bfloat16* wrt = WrT + (size_t)dir * G4 * HH;
    unsigned* bkd = bk + (size_t)dir * 2 * BB * HH;
    unsigned* fsd = fast + (size_t)dir * 2 * BB * HH;
    const unsigned* gfl = flags + (g << 5);
    unsigned* myflag = flags + (g << 5) + member;

    // persistent weight fragments (gate's 16 cols x full K=512)
    short8 bfrag[16];
    {
        const short8* wp = (const short8*)(wrt + (size_t)(gate*HH + h0 + lm) * HH + lk8);
        #pragma unroll
        for (int kc = 0; kc < 16; ++kc) bfrag[kc] = wp[kc*4];
    }

    __shared__ unsigned short htile[16][520];
    __shared__ float zbuf[4][16][17];

    int er = tid >> 3, ec = (tid & 7) * 2;   // epilogue mapping (tid<128)
    float c0st = 0.f, c1st = 0.f;
    int zr = (lane >> 4) * 4;

    bool fastok = true;
    int fallcnt = 0;

    for (int t = 0; t < TT; ++t) {
        int tok = dir ? (TT - 1 - t) : t;
        size_t soff = (size_t)(t & 1) * BB * HH + (size_t)r0 * HH;
        const unsigned long long pat =
            ((unsigned long long)(unsigned)t << 48) |
            ((unsigned long long)(unsigned)t << 16);

        // xz prefetch issued BEFORE detection (in flight during poll)
        float xzv[4];
        #pragma unroll
        for (int r = 0; r < 4; ++r) {
            int n = (r0 + zr + r) * TT + tok;
            xzv[r] = __bfloat162float(xz[(size_t)n * G4 + gate*HH + h0 + lm]);
        }

        unsigned long long v[16];
        bool ok = false;
        if (fastok) {
            const unsigned long long* fsrc = (const unsigned long long*)(fsd + soff);
            // (1) speculative read — tags embedded, 1 RT in the common case
            load16_sc0(fsrc, tid, v);
            unsigned long long bad = 0;
            #pragma unroll
            for (int q = 0; q < 16; ++q)
                bad |= (v[q] ^ pat) & 0xFFFF0000FFFF0000ULL;
            if (__all(bad == 0)) {
                ok = true;
            } else {
                // (2) cheap flag poll: 1 dword/lane/round (128 B/block/round)
                unsigned need = (unsigned)t;
                bool flagok = false;
                for (int spin = 0; spin < 96; ++spin) {
                    unsigned f = load_u32_sc0(gfl + (lane & 31));
                    if (__all(f >= need)) { flagok = true; break; }
                    __builtin_amdgcn_s_sleep(2);
                }
                if (flagok) {
                    // (3) one final data read; flag implies visible in this L2
                    load16_sc0(fsrc, tid, v);
                    bad = 0;
                    #pragma unroll
                    for (int q = 0; q < 16; ++q)
                        bad |= (v[q] ^ pat) & 0xFFFF0000FFFF0000ULL;
                    if (__all(bad == 0)) ok = true;
                }
                if (!ok) { if (++fallcnt >= 3) fastok = false; }
            }
        }
        if (!ok) {
            // proven R5 backup: agent-scope tag-in-data poll at L3
            const unsigned long long* bsrc = (const unsigned long long*)(bkd + soff);
            for (;;) {
                #pragma unroll
                for (int q = 0; q < 16; ++q)
                    v[q] = __hip_atomic_load(bsrc + tid + 256*q,
                            __ATOMIC_RELAXED, __HIP_MEMORY_SCOPE_AGENT);
                unsigned long long bad = 0;
                #pragma unroll
                for (int q = 0; q < 16; ++q)
                    bad |= (v[q] ^ pat) & 0xFFFF0000FFFF0000ULL;
                if (bad == 0) break;
                __builtin_amdgcn_s_sleep(2);
            }
        }

        // stage into LDS (strip tags): q -> row q, colpair tid
        #pragma unroll
        for (int q = 0; q < 16; ++q) {
            unsigned lo = (unsigned)(v[q] & 0xffffu);
            unsigned hi = (unsigned)((v[q] >> 32) & 0xffffu);
            *(unsigned*)&htile[q][tid * 2] = lo | (hi << 16);
        }
        __syncthreads();

        floatx4 acc = {};
        #pragma unroll
        for (int kc = 0; kc < 16; ++kc) {
            short8 a = *(const short8*)&htile[lm][kc * 32 + lk8];
            acc = __builtin_amdgcn_mfma_f32_16x16x32_bf16(a, bfrag[kc], acc, 0,0,0);
        }

        #pragma unroll
        for (int r = 0; r < 4; ++r)
            zbuf[gate][zr + r][lm] = acc[r] + xzv[r];
        __syncthreads();

        if (tid < 128) {
            float zi0 = zbuf[0][er][ec],   zi1 = zbuf[0][er][ec+1];
            float zf0 = zbuf[1][er][ec],   zf1 = zbuf[1][er][ec+1];
            float zg0 = zbuf[2][er][ec],   zg1 = zbuf[2][er][ec+1];
            float zo0 = zbuf[3][er][ec],   zo1 = zbuf[3][er][ec+1];
            float si0 = 1.f/(1.f+__expf(-zi0)), si1 = 1.f/(1.f+__expf(-zi1));
            float sf0 = 1.f/(1.f+__expf(-zf0)), sf1 = 1.f/(1.f+__expf(-zf1));
            float so0 = 1.f/(1.f+__expf(-zo0)), so1 = 1.f/(1.f+__expf(-zo1));
            c0st = sf0 * c0st + si0 * tanhf(zg0);
            c1st = sf1 * c1st + si1 * tanhf(zg1);
            float h0v = so0 * tanhf(c0st);
            float h1v = so1 * tanhf(c1st);
            unsigned u0 = (unsigned)__builtin_bit_cast(unsigned short, __float2bfloat16(h0v));
            unsigned u1 = (unsigned)__builtin_bit_cast(unsigned short, __float2bfloat16(h1v));
            unsigned tg = (unsigned)(t + 1) << 16;
            unsigned long long pay =
                ((unsigned long long)(tg | u1) << 32) | (unsigned long long)(tg | u0);
            size_t eoff = (size_t)((t+1) & 1) * BB * HH + (size_t)(r0 + er) * HH + h0 + ec;
            store_sc0((unsigned long long*)(fsd + eoff), pay);          // fast (L2)
            __hip_atomic_store((unsigned long long*)(bkd + eoff), pay,
                               __ATOMIC_RELAXED, __HIP_MEMORY_SCOPE_AGENT); // backup (L3)
            *(unsigned*)(hs + ((size_t)(r0 + er) * TT + tok) * HH + h0 + ec) =
                u0 | (u1 << 16);
        }
        __syncthreads();   // drain: all waves' data stores ack'd in L2/L3
        if (tid == 0)
            store_u32_sc0(myflag, (unsigned)(t + 1));   // flag AFTER data drain
    }
}

// ---------------------------------------------------------------------------
// logits via MFMA: 64 tokens/block (4 waves x 16), K=1024, N=16 (9 used)
// ---------------------------------------------------------------------------
__global__ __launch_bounds__(256) void logits_kernel(
    const __hip_bfloat16* __restrict__ hs_f, const __hip_bfloat16* __restrict__ hs_b,
    const __hip_bfloat16* __restrict__ WdT, const float* __restrict__ bd,
    float* __restrict__ out)
{
    int n0 = blockIdx.x * 64;
    int wave = threadIdx.x >> 6, lane = threadIdx.x & 63;
    int lm = lane & 15, lk8 = (lane >> 4) * 8;
    int nw = n0 + wave * 16;
    const short8* af = (const short8*)(hs_f + (size_t)(nw + lm) * HH + lk8);
    const short8* ab = (const short8*)(hs_b + (size_t)(nw + lm) * HH + lk8);
    const short8* bw = (const short8*)(WdT + (size_t)lm * 1024 + lk8);
    floatx4 acc = {};
    #pragma unroll
    for (int kc = 0; kc < 16; ++kc) {
        acc = __builtin_amdgcn_mfma_f32_16x16x32_bf16(af[kc*4], bw[kc*4], acc, 0,0,0);
        acc = __builtin_amdgcn_mfma_f32_16x16x32_bf16(ab[kc*4], bw[(kc+16)*4], acc, 0,0,0);
    }
    if (lm < LL) {
        float bv = bd[lm];
        #pragma unroll
        for (int r = 0; r < 4; ++r) {
            int n = nw + (lane >> 4) * 4 + r;
            out[(size_t)n * LL + lm] = acc[r] + bv;
        }
    }
}

// ---------------------------------------------------------------------------
// CRF: fused lens + log-likelihood + Viterbi. One block/batch, 256 threads.
// ---------------------------------------------------------------------------
__global__ __launch_bounds__(256) void crf_kernel(
    const float* __restrict__ logits, const int* __restrict__ text,
    const int* __restrict__ labels, const float* __restrict__ trans,
    float* __restrict__ out_lens, float* __restrict__ out_ll,
    float* __restrict__ out_tags)
{
    int b = blockIdx.x, tid = threadIdx.x;
    const float* lg = logits + (size_t)b * TT * LL;
    const int* lab = labels + b * TT;

    __shared__ float lgs[TT * LL];
    __shared__ float trs[81];
    __shared__ unsigned char bps[255 * LL + 1];
    __shared__ float partial[256];
    __shared__ int ired[256];
    __shared__ float tagf[TT];

    for (int i = tid; i < TT * LL; i += 256) lgs[i] = lg[i];
    if (tid < 81) trs[tid] = trans[tid];
    ired[tid] = (text[b * TT + tid] != 0) ? 1 : 0;
    __syncthreads();
    for (int s = 128; s > 0; s >>= 1) {
        if (tid < s) ired[tid] += ired[tid + s];
        __syncthreads();
    }
    int len = ired[0];
    if (tid == 0) out_lens[b] = (float)len;

    float up = 0.f;
    for (int t = tid; t < TT; t += 256) {
        float m = (t < len) ? 1.f : 0.f;
        up += m * lgs[t * LL + lab[t]];
        if (t >= 1) up += m * trs[lab[t - 1] * LL + lab[t]];
    }
    partial[tid] = up;
    __syncthreads();
    for (int s = 128; s > 0; s >>= 1) {
        if (tid < s) partial[tid] += partial[tid + s];
        __syncthreads();
    }

    if (tid < 64) {
        int lane = tid;
        int j = (lane < LL) ? lane : 0;
        float trj[LL];
        #pragma unroll
        for (int i = 0; i < LL; ++i) trj[i] = trs[i * LL + j];
        float alpha = lgs[j];
        float vit = alpha;
        for (int t = 1; t < TT; ++t) {
            bool m = t < len;
            float lgv = lgs[t * LL + j];
            float ta[LL];
            float mx = -1e30f, bv = -1e30f; int bi = 0;
            #pragma unroll
            for (int i = 0; i < LL; ++i) {
                float av = __shfl(alpha, i);
                float vv = __shfl(vit, i);
                ta[i] = av + trj[i];
                mx = fmaxf(mx, ta[i]);
                float sv = vv + trj[i];
                if (sv > bv) { bv = sv; bi = i; }
            }
            float s = 0.f;
            #pragma unroll
            for (int i = 0; i < LL; ++i) s += __expf(ta[i] - mx);
            float newa = mx + __logf(s) + lgv;
            float newv = bv + lgv;
            if (m) { alpha = newa; vit = newv; }
            if (lane < LL) bps[(t - 1) * LL + lane] = (unsigned char)(m ? bi : lane);
        }
        float aX[LL], vX[LL];
        #pragma unroll
        for (int i = 0; i < LL; ++i) { aX[i] = __shfl(alpha, i); vX[i] = __shfl(vit, i); }
        if (lane == 0) {
            float mx = -1e30f;
            #pragma unroll
            for (int i = 0; i < LL; ++i) mx = fmaxf(mx, aX[i]);
            float s = 0.f;
            #pragma unroll
            for (int i = 0; i < LL; ++i) s += __expf(aX[i] - mx);
            out_ll[b] = partial[0] - (mx + __logf(s));

            float bvv = vX[0]; int last = 0;
            #pragma unroll
            for (int i = 1; i < LL; ++i) if (vX[i] > bvv) { bvv = vX[i]; last = i; }
            tagf[TT - 1] = (float)last;
            int tg = last;
            for (int s2 = TT - 2; s2 >= 0; --s2) {
                tg = bps[s2 * LL + tg];
                tagf[s2] = (float)tg;
            }
        }
    }
    __syncthreads();
    out_tags[b * TT + tid] = tagf[tid];
}

// ---------------------------------------------------------------------------
extern "C" void kernel_launch(void* const* d_in, const int* in_sizes, int n_in,
                              void* d_out, int out_size, void* d_ws, size_t ws_size,
                              hipStream_t stream)
{
    const int*   text  = (const int*)d_in[0];
    const int*   sent  = (const int*)d_in[1];
    const int*   labels= (const int*)d_in[2];
    const float* wemb  = (const float*)d_in[3];
    const float* semb  = (const float*)d_in[4];
    const float* Wk_f  = (const float*)d_in[5];
    const float* Wr_f  = (const float*)d_in[6];
    const float* b_f   = (const float*)d_in[7];
    const float* Wk_b  = (const float*)d_in[8];
    const float* Wr_b  = (const float*)d_in[9];
    const float* b_b   = (const float*)d_in[10];
    const float* Wd    = (const float*)d_in[11];
    const float* bd    = (const float*)d_in[12];
    const float* trans = (const float*)d_in[13];
    float* out = (float*)d_out;

    char* ws = (char*)d_ws;
    __hip_bfloat16* xz_f = (__hip_bfloat16*)(ws + XZF_OFF);
    __hip_bfloat16* xz_b = (__hip_bfloat16*)(ws + XZB_OFF);
    __hip_bfloat16* hs_f = (__hip_bfloat16*)(ws + HSF_OFF);
    __hip_bfloat16* hs_b = (__hip_bfloat16*)(ws + HSB_OFF);
    __hip_bfloat16* xg   = (__hip_bfloat16*)(ws + XG_OFF);
    __hip_bfloat16* WkT  = (__hip_bfloat16*)(ws + WKT_OFF);
    __hip_bfloat16* WrT  = (__hip_bfloat16*)(ws + WRT_OFF);
    unsigned*       bk   = (unsigned*)(ws + BK_OFF);
    unsigned*       fast = (unsigned*)(ws + FAST_OFF);
    unsigned*       flg  = (unsigned*)(ws + FLAGS_OFF);
    __hip_bfloat16* WdT  = (__hip_bfloat16*)(ws + WDT_OFF);

    prep_xg <<<NT,  256, 0, stream>>>(text, sent, wemb, semb, xg);
    transpose_w<<<dim3(G4/64, (KP+63)/64, 2), 256, 0, stream>>>(Wk_f, Wk_b, WkT, DD, KP);
    transpose_w<<<dim3(G4/64, HH/64, 2),      256, 0, stream>>>(Wr_f, Wr_b, WrT, HH, HH);
    // zero backup + fast + flags (tag/flag 0 == h(0) = 0)
    hipMemsetAsync(ws + BK_OFF, 0, 2 * EX_BYTES + 1024, stream);

    embed_gemm<<<dim3(NT/128, G4/64), 256, 0, stream>>>(
        xg, WkT, b_f, b_b, xz_f, xz_b);

    {
        void* args[] = { (void*)&xz_f, (void*)&xz_b, (void*)&WrT,
                         (void*)&bk, (void*)&fast, (void*)&flg,
                         (void*)&hs_f, (void*)&hs_b };
        hipLaunchCooperativeKernel((const void*)lstm_coop, dim3(256), dim3(256),
                                   args, 0, stream);
    }

    prep_wdT<<<16, 256, 0, stream>>>(Wd, WdT);   // aliases dead xz_f
    logits_kernel<<<NT/64, 256, 0, stream>>>(hs_f, hs_b, WdT, bd, out + OUT_LOGITS);
    crf_kernel<<<BB, 256, 0, stream>>>(out + OUT_LOGITS, text, labels, trans,
                                       out + OUT_LENS, out + OUT_LL, out + OUT_TAGS);
}

// Round 7
// 1345.271 us; speedup vs baseline: 4.2612x; 1.0713x over previous
//
#include <hip/hip_runtime.h>
#include <hip/hip_bf16.h>
#include <math.h>

// Problem constants
#define BB 64
#define TT 256
#define EE 300
#define DD 600
#define KP 608        // K padded to 19*32 for MFMA
#define HH 512
#define G4 2048
#define LL 9
#define NT (BB*TT)

typedef __attribute__((ext_vector_type(8))) short short8;   // 8 bf16
typedef __attribute__((ext_vector_type(4))) float floatx4;  // MFMA acc

// ---------------- Workspace layout (bytes) ----------------
#define XZF_OFF  ((size_t)0)
#define XZ_BYTES ((size_t)NT * G4 * 2)                  // 67108864
#define XZB_OFF  (XZF_OFF + XZ_BYTES)
#define HSR_OFF  (XZB_OFF + XZ_BYTES)                   // hs region, 33554432
#define HS_BYTES ((size_t)NT * HH * 2)                  // 16777216
#define HSF_OFF  (HSR_OFF)
#define HSB_OFF  (HSR_OFF + HS_BYTES)
// aliases inside hs region (dead before lstm writes hs):
#define XG_OFF   (HSR_OFF)                              // 16384*608*2
#define WKT_OFF  (HSR_OFF + 19922944)                   // 2*2048*608*2
#define WRT_OFF  (HSR_OFF + (size_t)2 * HS_BYTES)       // 2*2048*512*2 = 4194304
#define BK_OFF   (WRT_OFF + 4194304)                    // backup tagged: 524288
#define FAST_OFF (BK_OFF + 524288)                      // fast tagged:   524288
#define EX_BYTES ((size_t)2 * 2 * BB * HH * 4)          // 524288 each
#define FLAGS_OFF (FAST_OFF + 524288)                   // 8 groups * 32 u32 = 1024
// WdT aliases xz_f (dead after lstm), written post-lstm:
#define WDT_OFF  XZF_OFF                                // 16*1024*2 = 32768

// Output layout (floats)
#define OUT_LOGITS 0
#define OUT_LENS   (BB*TT*LL)
#define OUT_LL     (OUT_LENS + BB)
#define OUT_TAGS   (OUT_LL + BB)

// ---------------------------------------------------------------------------
// Prep 1: gather embeddings -> xg[n][608] bf16 (zero-padded K)
// ---------------------------------------------------------------------------
__global__ __launch_bounds__(256) void prep_xg(
    const int* __restrict__ text, const int* __restrict__ sent,
    const float* __restrict__ wemb, const float* __restrict__ semb,
    __hip_bfloat16* __restrict__ xg)
{
    int n = blockIdx.x;
    int ti = text[n], si = sent[n];
    __hip_bfloat16* o = xg + (size_t)n * KP;
    for (int k = threadIdx.x; k < KP; k += 256) {
        float v = 0.f;
        if (k < EE)      v = wemb[(size_t)ti * EE + k];
        else if (k < DD) v = semb[(size_t)si * EE + (k - EE)];
        o[k] = __float2bfloat16(v);
    }
}

// ---------------------------------------------------------------------------
// Prep 2: LDS-tiled transpose + bf16 convert. W[dir]=[Din][2048] f32 ->
// out[dir]=[2048][Dpad] bf16
// ---------------------------------------------------------------------------
__global__ __launch_bounds__(256) void transpose_w(
    const float* __restrict__ Wf, const float* __restrict__ Wb,
    __hip_bfloat16* __restrict__ outT, int Din, int Dpad)
{
    int dir = blockIdx.z;
    const float* W = dir ? Wb : Wf;
    __hip_bfloat16* o = outT + (size_t)dir * G4 * Dpad;
    int n0 = blockIdx.x * 64, d0 = blockIdx.y * 64;
    __shared__ float tile[64][65];
    int c = threadIdx.x & 63, r4 = threadIdx.x >> 6;
    #pragma unroll
    for (int rr = 0; rr < 64; rr += 4) {
        int d = d0 + rr + r4;
        tile[rr + r4][c] = (d < Din) ? W[(size_t)d * G4 + n0 + c] : 0.f;
    }
    __syncthreads();
    #pragma unroll
    for (int rr = 0; rr < 64; rr += 4) {
        int n = n0 + rr + r4;
        int d = d0 + c;
        if (d < Dpad) o[(size_t)n * Dpad + d] = __float2bfloat16(tile[c][rr + r4]);
    }
}

// ---------------------------------------------------------------------------
// Prep 3 (post-lstm): WdT[16][1024] bf16, WdT[c][k] = Wd[k][c] (c<9 else 0)
// ---------------------------------------------------------------------------
__global__ __launch_bounds__(256) void prep_wdT(
    const float* __restrict__ Wd, __hip_bfloat16* __restrict__ WdT)
{
    for (int i = threadIdx.x + blockIdx.x * 256; i < 16 * 1024; i += gridDim.x * 256) {
        int nn = i >> 10, k = i & 1023;
        WdT[i] = __float2bfloat16(nn < LL ? Wd[(size_t)k * LL + nn] : 0.f);
    }
}

// ---------------------------------------------------------------------------
// Embed GEMM. R7: 128x128 block tile, 4 waves each owning 64x64 (4x4 16x16
// sub-tiles). Per kc per wave: 4 A + 4 B fragment loads feed 16 MFMAs —
// loads/MFMA 0.75 -> 0.5 (−33% L2 traffic per FLOP vs 128x64). Dir-fold
// retained (A-tile L2 reuse). acc = 64 VGPR; ~140 total, no spill expected.
// ---------------------------------------------------------------------------
__global__ __launch_bounds__(256) void embed_gemm(
    const __hip_bfloat16* __restrict__ xg,
    const __hip_bfloat16* __restrict__ WkT,
    const float* __restrict__ b_f, const float* __restrict__ b_b,
    __hip_bfloat16* __restrict__ xz_f, __hip_bfloat16* __restrict__ xz_b)
{
    int n0 = blockIdx.x * 128;
    int c0 = blockIdx.y * 128;
    int wave = threadIdx.x >> 6, lane = threadIdx.x & 63;
    int m0 = (wave & 1) * 64;
    int nn0 = (wave >> 1) * 64;
    int lm = lane & 15, lk8 = (lane >> 4) * 8;

    const short8 *ap[4];
    #pragma unroll
    for (int i = 0; i < 4; ++i)
        ap[i] = (const short8*)(xg + (size_t)(n0 + m0 + i*16 + lm) * KP + lk8);

    for (int dir = 0; dir < 2; ++dir) {
        const __hip_bfloat16* wt = WkT + (size_t)dir * G4 * KP;
        const float* bias = dir ? b_b : b_f;
        __hip_bfloat16* xz = dir ? xz_b : xz_f;

        const short8 *bp[4];
        #pragma unroll
        for (int i = 0; i < 4; ++i)
            bp[i] = (const short8*)(wt + (size_t)(c0 + nn0 + i*16 + lm) * KP + lk8);

        floatx4 acc[4][4] = {};
        for (int kc = 0; kc < KP/32; ++kc) {
            short8 a0 = ap[0][kc*4], a1 = ap[1][kc*4], a2 = ap[2][kc*4], a3 = ap[3][kc*4];
            short8 b0 = bp[0][kc*4], b1 = bp[1][kc*4], b2 = bp[2][kc*4], b3 = bp[3][kc*4];
            acc[0][0] = __builtin_amdgcn_mfma_f32_16x16x32_bf16(a0, b0, acc[0][0], 0,0,0);
            acc[0][1] = __builtin_amdgcn_mfma_f32_16x16x32_bf16(a0, b1, acc[0][1], 0,0,0);
            acc[0][2] = __builtin_amdgcn_mfma_f32_16x16x32_bf16(a0, b2, acc[0][2], 0,0,0);
            acc[0][3] = __builtin_amdgcn_mfma_f32_16x16x32_bf16(a0, b3, acc[0][3], 0,0,0);
            acc[1][0] = __builtin_amdgcn_mfma_f32_16x16x32_bf16(a1, b0, acc[1][0], 0,0,0);
            acc[1][1] = __builtin_amdgcn_mfma_f32_16x16x32_bf16(a1, b1, acc[1][1], 0,0,0);
            acc[1][2] = __builtin_amdgcn_mfma_f32_16x16x32_bf16(a1, b2, acc[1][2], 0,0,0);
            acc[1][3] = __builtin_amdgcn_mfma_f32_16x16x32_bf16(a1, b3, acc[1][3], 0,0,0);
            acc[2][0] = __builtin_amdgcn_mfma_f32_16x16x32_bf16(a2, b0, acc[2][0], 0,0,0);
            acc[2][1] = __builtin_amdgcn_mfma_f32_16x16x32_bf16(a2, b1, acc[2][1], 0,0,0);
            acc[2][2] = __builtin_amdgcn_mfma_f32_16x16x32_bf16(a2, b2, acc[2][2], 0,0,0);
            acc[2][3] = __builtin_amdgcn_mfma_f32_16x16x32_bf16(a2, b3, acc[2][3], 0,0,0);
            acc[3][0] = __builtin_amdgcn_mfma_f32_16x16x32_bf16(a3, b0, acc[3][0], 0,0,0);
            acc[3][1] = __builtin_amdgcn_mfma_f32_16x16x32_bf16(a3, b1, acc[3][1], 0,0,0);
            acc[3][2] = __builtin_amdgcn_mfma_f32_16x16x32_bf16(a3, b2, acc[3][2], 0,0,0);
            acc[3][3] = __builtin_amdgcn_mfma_f32_16x16x32_bf16(a3, b3, acc[3][3], 0,0,0);
        }

        int lr = (lane >> 4) * 4;
        #pragma unroll
        for (int ni = 0; ni < 4; ++ni) {
            int col = c0 + nn0 + ni*16 + lm;
            float bs = bias[col];
            #pragma unroll
            for (int mi = 0; mi < 4; ++mi) {
                #pragma unroll
                for (int r = 0; r < 4; ++r) {
                    int row = n0 + m0 + mi*16 + lr + r;
                    xz[(size_t)row * G4 + col] = __float2bfloat16(acc[mi][ni][r] + bs);
                }
            }
        }
    }
}

// ---------------------------------------------------------------------------
// sc0 (L1-bypass, L2-served) pipelined primitives
// ---------------------------------------------------------------------------
__device__ __forceinline__ void load16_sc0(const unsigned long long* base,
                                           int tid, unsigned long long* v)
{
    #pragma unroll
    for (int q = 0; q < 16; ++q) {
        const unsigned long long* ap = base + tid + 256 * q;
        asm volatile("global_load_dwordx2 %0, %1, off sc0"
                     : "=v"(v[q]) : "v"(ap));
    }
    asm volatile("s_waitcnt vmcnt(0)" ::: "memory");
}

__device__ __forceinline__ void store_sc0(unsigned long long* p,
                                          unsigned long long val)
{
    asm volatile("global_store_dwordx2 %0, %1, off sc0"
                 :: "v"(p), "v"(val) : "memory");
}

__device__ __forceinline__ unsigned load_u32_sc0(const unsigned* p)
{
    unsigned r;
    asm volatile("global_load_dword %0, %1, off sc0\n\ts_waitcnt vmcnt(0)"
                 : "=v"(r) : "v"(p) : "memory");
    return r;
}

__device__ __forceinline__ void store_u32_sc0(unsigned* p, unsigned v)
{
    asm volatile("global_store_dword %0, %1, off sc0" :: "v"(p), "v"(v) : "memory");
}

// ---------------------------------------------------------------------------
// Persistent LSTM. 256 blocks x 256 threads, cooperative. (R0-verbatim:
// the verified ~930 µs local optimum. Spec-read-first tagged protocol.)
// g = blk&7 (XCD residue class — confirmed L2-local by prior FETCH collapse),
// member = blk>>3. Fast path: (1) SPECULATIVE tagged-data read (1 RT when
// producers ahead); (2) on miss, poll 128B FLAG array (not the 32KB tile);
// (3) one final data read. Producer: fast+backup+hs stores -> drain barrier
// -> flag=t+1 (flag implies data visible in same L2). Backup (L3,
// tag-in-data): bounded flag spins fall back to it; sticky-disable after 3
// failed steps. Never deadlocks.
// ---------------------------------------------------------------------------
__global__ __launch_bounds__(256, 1) void lstm_coop(
    const __hip_bfloat16* __restrict__ xz_f, const __hip_bfloat16* __restrict__ xz_b,
    const __hip_bfloat16* __restrict__ WrT,   // [2][2048][512]
    unsigned* __restrict__ bk,                // backup tagged [2][2][64][512]
    unsigned* __restrict__ fast,              // fast   tagged [2][2][64][512]
    unsigned* __restrict__ flags,             // [8 groups][32 members]
    __hip_bfloat16* __restrict__ hs_f, __hip_bfloat16* __restrict__ hs_b)
{
    int blk = blockIdx.x;
    int g = blk & 7;              // group = XCD residue class
    int member = blk >> 3;        // 0..31
    int dir = g >> 2;
    int r0 = (g & 3) * 16;
    int h0 = member * 16;
    int tid = threadIdx.x;
    int gate = tid >> 6, lane = tid & 63;
    int lm = lane & 15, lk8 = (lane >> 4) * 8;

    const __hip_bfloat16* xz = dir ? xz_b : xz_f;
    __hip_bfloat16* hs = dir ? hs_b : hs_f;
    const __hip_bfloat16* wrt = WrT + (size_t)dir * G4 * HH;
    unsigned* bkd = bk + (size_t)dir * 2 * BB * HH;
    unsigned* fsd = fast + (size_t)dir * 2 * BB * HH;
    const unsigned* gfl = flags + (g << 5);
    unsigned* myflag = flags + (g << 5) + member;

    // persistent weight fragments (gate's 16 cols x full K=512)
    short8 bfrag[16];
    {
        const short8* wp = (const short8*)(wrt + (size_t)(gate*HH + h0 + lm) * HH + lk8);
        #pragma unroll
        for (int kc = 0; kc < 16; ++kc) bfrag[kc] = wp[kc*4];
    }

    __shared__ unsigned short htile[16][520];
    __shared__ float zbuf[4][16][17];

    int er = tid >> 3, ec = (tid & 7) * 2;   // epilogue mapping (tid<128)
    float c0st = 0.f, c1st = 0.f;
    int zr = (lane >> 4) * 4;

    bool fastok = true;
    int fallcnt = 0;

    for (int t = 0; t < TT; ++t) {
        int tok = dir ? (TT - 1 - t) : t;
        size_t soff = (size_t)(t & 1) * BB * HH + (size_t)r0 * HH;
        const unsigned long long pat =
            ((unsigned long long)(unsigned)t << 48) |
            ((unsigned long long)(unsigned)t << 16);

        // xz prefetch issued BEFORE detection (in flight during poll)
        float xzv[4];
        #pragma unroll
        for (int r = 0; r < 4; ++r) {
            int n = (r0 + zr + r) * TT + tok;
            xzv[r] = __bfloat162float(xz[(size_t)n * G4 + gate*HH + h0 + lm]);
        }

        unsigned long long v[16];
        bool ok = false;
        if (fastok) {
            const unsigned long long* fsrc = (const unsigned long long*)(fsd + soff);
            // (1) speculative read — tags embedded, 1 RT in the common case
            load16_sc0(fsrc, tid, v);
            unsigned long long bad = 0;
            #pragma unroll
            for (int q = 0; q < 16; ++q)
                bad |= (v[q] ^ pat) & 0xFFFF0000FFFF0000ULL;
            if (__all(bad == 0)) {
                ok = true;
            } else {
                // (2) cheap flag poll: 1 dword/lane/round (128 B/block/round)
                unsigned need = (unsigned)t;
                bool flagok = false;
                for (int spin = 0; spin < 96; ++spin) {
                    unsigned f = load_u32_sc0(gfl + (lane & 31));
                    if (__all(f >= need)) { flagok = true; break; }
                    __builtin_amdgcn_s_sleep(2);
                }
                if (flagok) {
                    // (3) one final data read; flag implies visible in this L2
                    load16_sc0(fsrc, tid, v);
                    bad = 0;
                    #pragma unroll
                    for (int q = 0; q < 16; ++q)
                        bad |= (v[q] ^ pat) & 0xFFFF0000FFFF0000ULL;
                    if (__all(bad == 0)) ok = true;
                }
                if (!ok) { if (++fallcnt >= 3) fastok = false; }
            }
        }
        if (!ok) {
            // proven backup: agent-scope tag-in-data poll at L3
            const unsigned long long* bsrc = (const unsigned long long*)(bkd + soff);
            for (;;) {
                #pragma unroll
                for (int q = 0; q < 16; ++q)
                    v[q] = __hip_atomic_load(bsrc + tid + 256*q,
                            __ATOMIC_RELAXED, __HIP_MEMORY_SCOPE_AGENT);
                unsigned long long bad = 0;
                #pragma unroll
                for (int q = 0; q < 16; ++q)
                    bad |= (v[q] ^ pat) & 0xFFFF0000FFFF0000ULL;
                if (bad == 0) break;
                __builtin_amdgcn_s_sleep(2);
            }
        }

        // stage into LDS (strip tags): q -> row q, colpair tid
        #pragma unroll
        for (int q = 0; q < 16; ++q) {
            unsigned lo = (unsigned)(v[q] & 0xffffu);
            unsigned hi = (unsigned)((v[q] >> 32) & 0xffffu);
            *(unsigned*)&htile[q][tid * 2] = lo | (hi << 16);
        }
        __syncthreads();

        floatx4 acc = {};
        #pragma unroll
        for (int kc = 0; kc < 16; ++kc) {
            short8 a = *(const short8*)&htile[lm][kc * 32 + lk8];
            acc = __builtin_amdgcn_mfma_f32_16x16x32_bf16(a, bfrag[kc], acc, 0,0,0);
        }

        #pragma unroll
        for (int r = 0; r < 4; ++r)
            zbuf[gate][zr + r][lm] = acc[r] + xzv[r];
        __syncthreads();

        if (tid < 128) {
            float zi0 = zbuf[0][er][ec],   zi1 = zbuf[0][er][ec+1];
            float zf0 = zbuf[1][er][ec],   zf1 = zbuf[1][er][ec+1];
            float zg0 = zbuf[2][er][ec],   zg1 = zbuf[2][er][ec+1];
            float zo0 = zbuf[3][er][ec],   zo1 = zbuf[3][er][ec+1];
            float si0 = 1.f/(1.f+__expf(-zi0)), si1 = 1.f/(1.f+__expf(-zi1));
            float sf0 = 1.f/(1.f+__expf(-zf0)), sf1 = 1.f/(1.f+__expf(-zf1));
            float so0 = 1.f/(1.f+__expf(-zo0)), so1 = 1.f/(1.f+__expf(-zo1));
            c0st = sf0 * c0st + si0 * tanhf(zg0);
            c1st = sf1 * c1st + si1 * tanhf(zg1);
            float h0v = so0 * tanhf(c0st);
            float h1v = so1 * tanhf(c1st);
            unsigned u0 = (unsigned)__builtin_bit_cast(unsigned short, __float2bfloat16(h0v));
            unsigned u1 = (unsigned)__builtin_bit_cast(unsigned short, __float2bfloat16(h1v));
            unsigned tg = (unsigned)(t + 1) << 16;
            unsigned long long pay =
                ((unsigned long long)(tg | u1) << 32) | (unsigned long long)(tg | u0);
            size_t eoff = (size_t)((t+1) & 1) * BB * HH + (size_t)(r0 + er) * HH + h0 + ec;
            store_sc0((unsigned long long*)(fsd + eoff), pay);          // fast (L2)
            __hip_atomic_store((unsigned long long*)(bkd + eoff), pay,
                               __ATOMIC_RELAXED, __HIP_MEMORY_SCOPE_AGENT); // backup (L3)
            *(unsigned*)(hs + ((size_t)(r0 + er) * TT + tok) * HH + h0 + ec) =
                u0 | (u1 << 16);
        }
        __syncthreads();   // drain: all waves' data stores ack'd in L2/L3
        if (tid == 0)
            store_u32_sc0(myflag, (unsigned)(t + 1));   // flag AFTER data drain
    }
}

// ---------------------------------------------------------------------------
// logits via MFMA: 64 tokens/block (4 waves x 16), K=1024, N=16 (9 used)
// ---------------------------------------------------------------------------
__global__ __launch_bounds__(256) void logits_kernel(
    const __hip_bfloat16* __restrict__ hs_f, const __hip_bfloat16* __restrict__ hs_b,
    const __hip_bfloat16* __restrict__ WdT, const float* __restrict__ bd,
    float* __restrict__ out)
{
    int n0 = blockIdx.x * 64;
    int wave = threadIdx.x >> 6, lane = threadIdx.x & 63;
    int lm = lane & 15, lk8 = (lane >> 4) * 8;
    int nw = n0 + wave * 16;
    const short8* af = (const short8*)(hs_f + (size_t)(nw + lm) * HH + lk8);
    const short8* ab = (const short8*)(hs_b + (size_t)(nw + lm) * HH + lk8);
    const short8* bw = (const short8*)(WdT + (size_t)lm * 1024 + lk8);
    floatx4 acc = {};
    #pragma unroll
    for (int kc = 0; kc < 16; ++kc) {
        acc = __builtin_amdgcn_mfma_f32_16x16x32_bf16(af[kc*4], bw[kc*4], acc, 0,0,0);
        acc = __builtin_amdgcn_mfma_f32_16x16x32_bf16(ab[kc*4], bw[(kc+16)*4], acc, 0,0,0);
    }
    if (lm < LL) {
        float bv = bd[lm];
        #pragma unroll
        for (int r = 0; r < 4; ++r) {
            int n = nw + (lane >> 4) * 4 + r;
            out[(size_t)n * LL + lm] = acc[r] + bv;
        }
    }
}

// ---------------------------------------------------------------------------
// CRF: fused lens + log-likelihood + Viterbi. One block/batch, 256 threads.
// ---------------------------------------------------------------------------
__global__ __launch_bounds__(256) void crf_kernel(
    const float* __restrict__ logits, const int* __restrict__ text,
    const int* __restrict__ labels, const float* __restrict__ trans,
    float* __restrict__ out_lens, float* __restrict__ out_ll,
    float* __restrict__ out_tags)
{
    int b = blockIdx.x, tid = threadIdx.x;
    const float* lg = logits + (size_t)b * TT * LL;
    const int* lab = labels + b * TT;

    __shared__ float lgs[TT * LL];
    __shared__ float trs[81];
    __shared__ unsigned char bps[255 * LL + 1];
    __shared__ float partial[256];
    __shared__ int ired[256];
    __shared__ float tagf[TT];

    for (int i = tid; i < TT * LL; i += 256) lgs[i] = lg[i];
    if (tid < 81) trs[tid] = trans[tid];
    ired[tid] = (text[b * TT + tid] != 0) ? 1 : 0;
    __syncthreads();
    for (int s = 128; s > 0; s >>= 1) {
        if (tid < s) ired[tid] += ired[tid + s];
        __syncthreads();
    }
    int len = ired[0];
    if (tid == 0) out_lens[b] = (float)len;

    float up = 0.f;
    for (int t = tid; t < TT; t += 256) {
        float m = (t < len) ? 1.f : 0.f;
        up += m * lgs[t * LL + lab[t]];
        if (t >= 1) up += m * trs[lab[t - 1] * LL + lab[t]];
    }
    partial[tid] = up;
    __syncthreads();
    for (int s = 128; s > 0; s >>= 1) {
        if (tid < s) partial[tid] += partial[tid + s];
        __syncthreads();
    }

    if (tid < 64) {
        int lane = tid;
        int j = (lane < LL) ? lane : 0;
        float trj[LL];
        #pragma unroll
        for (int i = 0; i < LL; ++i) trj[i] = trs[i * LL + j];
        float alpha = lgs[j];
        float vit = alpha;
        for (int t = 1; t < TT; ++t) {
            bool m = t < len;
            float lgv = lgs[t * LL + j];
            float ta[LL];
            float mx = -1e30f, bv = -1e30f; int bi = 0;
            #pragma unroll
            for (int i = 0; i < LL; ++i) {
                float av = __shfl(alpha, i);
                float vv = __shfl(vit, i);
                ta[i] = av + trj[i];
                mx = fmaxf(mx, ta[i]);
                float sv = vv + trj[i];
                if (sv > bv) { bv = sv; bi = i; }
            }
            float s = 0.f;
            #pragma unroll
            for (int i = 0; i < LL; ++i) s += __expf(ta[i] - mx);
            float newa = mx + __logf(s) + lgv;
            float newv = bv + lgv;
            if (m) { alpha = newa; vit = newv; }
            if (lane < LL) bps[(t - 1) * LL + lane] = (unsigned char)(m ? bi : lane);
        }
        float aX[LL], vX[LL];
        #pragma unroll
        for (int i = 0; i < LL; ++i) { aX[i] = __shfl(alpha, i); vX[i] = __shfl(vit, i); }
        if (lane == 0) {
            float mx = -1e30f;
            #pragma unroll
            for (int i = 0; i < LL; ++i) mx = fmaxf(mx, aX[i]);
            float s = 0.f;
            #pragma unroll
            for (int i = 0; i < LL; ++i) s += __expf(aX[i] - mx);
            out_ll[b] = partial[0] - (mx + __logf(s));

            float bvv = vX[0]; int last = 0;
            #pragma unroll
            for (int i = 1; i < LL; ++i) if (vX[i] > bvv) { bvv = vX[i]; last = i; }
            tagf[TT - 1] = (float)last;
            int tg = last;
            for (int s2 = TT - 2; s2 >= 0; --s2) {
                tg = bps[s2 * LL + tg];
                tagf[s2] = (float)tg;
            }
        }
    }
    __syncthreads();
    out_tags[b * TT + tid] = tagf[tid];
}

// ---------------------------------------------------------------------------
extern "C" void kernel_launch(void* const* d_in, const int* in_sizes, int n_in,
                              void* d_out, int out_size, void* d_ws, size_t ws_size,
                              hipStream_t stream)
{
    const int*   text  = (const int*)d_in[0];
    const int*   sent  = (const int*)d_in[1];
    const int*   labels= (const int*)d_in[2];
    const float* wemb  = (const float*)d_in[3];
    const float* semb  = (const float*)d_in[4];
    const float* Wk_f  = (const float*)d_in[5];
    const float* Wr_f  = (const float*)d_in[6];
    const float* b_f   = (const float*)d_in[7];
    const float* Wk_b  = (const float*)d_in[8];
    const float* Wr_b  = (const float*)d_in[9];
    const float* b_b   = (const float*)d_in[10];
    const float* Wd    = (const float*)d_in[11];
    const float* bd    = (const float*)d_in[12];
    const float* trans = (const float*)d_in[13];
    float* out = (float*)d_out;

    char* ws = (char*)d_ws;
    __hip_bfloat16* xz_f = (__hip_bfloat16*)(ws + XZF_OFF);
    __hip_bfloat16* xz_b = (__hip_bfloat16*)(ws + XZB_OFF);
    __hip_bfloat16* hs_f = (__hip_bfloat16*)(ws + HSF_OFF);
    __hip_bfloat16* hs_b = (__hip_bfloat16*)(ws + HSB_OFF);
    __hip_bfloat16* xg   = (__hip_bfloat16*)(ws + XG_OFF);
    __hip_bfloat16* WkT  = (__hip_bfloat16*)(ws + WKT_OFF);
    __hip_bfloat16* WrT  = (__hip_bfloat16*)(ws + WRT_OFF);
    unsigned*       bk   = (unsigned*)(ws + BK_OFF);
    unsigned*       fast = (unsigned*)(ws + FAST_OFF);
    unsigned*       flg  = (unsigned*)(ws + FLAGS_OFF);
    __hip_bfloat16* WdT  = (__hip_bfloat16*)(ws + WDT_OFF);

    prep_xg <<<NT,  256, 0, stream>>>(text, sent, wemb, semb, xg);
    transpose_w<<<dim3(G4/64, (KP+63)/64, 2), 256, 0, stream>>>(Wk_f, Wk_b, WkT, DD, KP);
    transpose_w<<<dim3(G4/64, HH/64, 2),      256, 0, stream>>>(Wr_f, Wr_b, WrT, HH, HH);
    // zero backup + fast + flags (tag/flag 0 == h(0) = 0)
    hipMemsetAsync(ws + BK_OFF, 0, 2 * EX_BYTES + 1024, stream);

    embed_gemm<<<dim3(NT/128, G4/128), 256, 0, stream>>>(
        xg, WkT, b_f, b_b, xz_f, xz_b);

    {
        void* args[] = { (void*)&xz_f, (void*)&xz_b, (void*)&WrT,
                         (void*)&bk, (void*)&fast, (void*)&flg,
                         (void*)&hs_f, (void*)&hs_b };
        hipLaunchCooperativeKernel((const void*)lstm_coop, dim3(256), dim3(256),
                                   args, 0, stream);
    }

    prep_wdT<<<16, 256, 0, stream>>>(Wd, WdT);   // aliases dead xz_f
    logits_kernel<<<NT/64, 256, 0, stream>>>(hs_f, hs_b, WdT, bd, out + OUT_LOGITS);
    crf_kernel<<<BB, 256, 0, stream>>>(out + OUT_LOGITS, text, labels, trans,
                                       out + OUT_LENS, out + OUT_LL, out + OUT_TAGS);
}